// Round 17
// baseline (74.954 us; speedup 1.0000x reference)
//
#include <hip/hip_runtime.h>
#include <hip/hip_bf16.h>

// out[b,w] = relu(sqrt(max(||x_b||^2 + ||w_w||^2 - 2*x_b.w_w, 0)) / sqrt(512))
// M=8192, N=4096, K=512. bf16 MFMA NT-GEMM.
// BARRIER-FREE design: 64x64 tile per 1-wave (64-thread) block, 8192 blocks.
// The wave stages its own A/B slices -> zero __syncthreads. Per K-step:
// ds_read x16 -> lgkmcnt(0) -> stage(t+1) -> MFMA x32 (covers load latency)
// -> vmcnt(0). Waves self-stagger; no barrier convoy, no block-wide drain.
// Same verified T2 XOR-swizzle pair and C/D mapping as the R11 champion.

typedef __bf16 bf16x8 __attribute__((ext_vector_type(8)));
typedef float f32x4 __attribute__((ext_vector_type(4)));

#define K_DIM 512
#define INV_SCALE 0.04419417382415922f  // 1/22.627417

__device__ __forceinline__ ushort f2bf(float f) {
  __hip_bfloat16 h = __float2bfloat16(f);
  return __builtin_bit_cast(ushort, h);
}

// fp32 -> bf16 convert + row sum of squares. One 128-thread block per row.
__global__ __launch_bounds__(128) void convert_kernel(
    const float* __restrict__ x, const float* __restrict__ w,
    ushort* __restrict__ xb, ushort* __restrict__ wb,
    float* __restrict__ xsq, float* __restrict__ wsq, int M) {
  int b = blockIdx.x;
  const float* src; ushort* dst; float* sq; int row;
  if (b < M) { src = x; dst = xb; sq = xsq; row = b; }
  else       { src = w; dst = wb; sq = wsq; row = b - M; }
  int t = threadIdx.x;
  float4 v = reinterpret_cast<const float4*>(src + (size_t)row * K_DIM)[t];
  ushort4 p;
  p.x = f2bf(v.x); p.y = f2bf(v.y); p.z = f2bf(v.z); p.w = f2bf(v.w);
  reinterpret_cast<ushort4*>(dst + (size_t)row * K_DIM)[t] = p;
  float s = v.x * v.x + v.y * v.y + v.z * v.z + v.w * v.w;
#pragma unroll
  for (int o = 32; o > 0; o >>= 1) s += __shfl_down(s, o, 64);
  __shared__ float red[2];
  if ((t & 63) == 0) red[t >> 6] = s;
  __syncthreads();
  if (t == 0) sq[row] = red[0] + red[1];
}

// LDS holds (row, ch) = global(row, ch ^ (row&7)); staging pre-swizzles the
// per-lane global source chunk (linear gll dest), reads XOR with row&7.
__global__ __launch_bounds__(64) void gemm_dist_kernel(
    const ushort* __restrict__ xb, const ushort* __restrict__ wb,
    const float* __restrict__ xsq, const float* __restrict__ wsq,
    float* __restrict__ out, int M, int N) {
  __shared__ ushort Asm[64 * 64];  // 8 KB
  __shared__ ushort Bsm[64 * 64];  // 8 KB

  const int ntM = M >> 6;                 // 128
  const int ntN = N >> 6;                 // 64
  const int nwg = gridDim.x;              // 8192
  const int bid = blockIdx.x;
  int tR, tC;
  if (ntM == 128 && ntN == 64 && nwg == 8192) {
    // 16x16-tile XCD groups (64x64 tiles): footprint 1+1 MB < 4 MB L2.
    // 32 groups (8 gRows x 4 gCols), 4 per XCD, row-major within group.
    const int xcd = bid & 7;
    const int seq = bid >> 3;                  // 0..1023
    const int gid = ((seq >> 8) << 3) + xcd;   // 0..31
    const int wi  = seq & 255;                 // 0..255
    tR = ((gid >> 2) << 4) + (wi >> 4);
    tC = ((gid & 3) << 4) + (wi & 15);
  } else {
    tR = bid / ntN;
    tC = bid - tR * ntN;
  }

  const int lane = threadIdx.x & 63;
  const int l15 = lane & 15, l4 = lane >> 4;

  const int rowA0 = tR << 6;
  const int rowB0 = tC << 6;

  f32x4 acc[4][4] = {};

  // Staging: 8 gll each for A and B; call c covers rows [c*8, c*8+8);
  // lane l -> row +(l>>3), source chunk pre-swizzled (l&7)^(l>>3)
  // (row&7 == l>>3) so the linear gll dest yields the swizzled layout.
  const int srow = lane >> 3;
  const int scol = ((lane & 7) ^ (lane >> 3)) << 3;
  const ushort* gA = xb + (size_t)(rowA0 + srow) * K_DIM + scol;
  const ushort* gB = wb + (size_t)(rowB0 + srow) * K_DIM + scol;

#define STAGEK(kt) do {                                                        \
    _Pragma("unroll")                                                          \
    for (int c8 = 0; c8 < 8; ++c8) {                                           \
      __builtin_amdgcn_global_load_lds(                                        \
          (const __attribute__((address_space(1))) void*)                      \
              (gA + (size_t)(c8 * 8) * K_DIM + (kt)),                          \
          (__attribute__((address_space(3))) void*)&Asm[(c8 * 8) * 64], 16, 0, 0); \
      __builtin_amdgcn_global_load_lds(                                        \
          (const __attribute__((address_space(1))) void*)                      \
              (gB + (size_t)(c8 * 8) * K_DIM + (kt)),                          \
          (__attribute__((address_space(3))) void*)&Bsm[(c8 * 8) * 64], 16, 0, 0); \
    } } while (0)

  STAGEK(0);
  asm volatile("s_waitcnt vmcnt(0)" : : : "memory");
  __builtin_amdgcn_sched_barrier(0);

  const int axor = l15 & 7;  // row&7 for this lane's fragment rows
#pragma unroll
  for (int t = 0; t < 8; ++t) {
    const int kt = t << 6;
    // Read ALL 16 fragments of tile t into registers.
    bf16x8 af[2][4], bg[2][4];
#pragma unroll
    for (int kk = 0; kk < 2; ++kk) {
      const int cx = (((kk << 2) + l4) ^ axor) << 3;  // swizzled chunk offset
#pragma unroll
      for (int i = 0; i < 4; ++i) {
        af[kk][i] = *reinterpret_cast<const bf16x8*>(
            &Asm[((i << 4) + l15) * 64 + cx]);
        bg[kk][i] = *reinterpret_cast<const bf16x8*>(
            &Bsm[((i << 4) + l15) * 64 + cx]);
      }
    }
    // All LDS reads of tile t complete -> safe to overwrite LDS.
    asm volatile("s_waitcnt lgkmcnt(0)" : : : "memory");
    __builtin_amdgcn_sched_barrier(0);
    if (t < 7) STAGEK(kt + 64);        // issue next-tile stage early
    __builtin_amdgcn_sched_barrier(0); // keep glls above the MFMA cluster
#pragma unroll
    for (int kk = 0; kk < 2; ++kk)
#pragma unroll
      for (int i = 0; i < 4; ++i)
#pragma unroll
        for (int j = 0; j < 4; ++j)
          acc[i][j] = __builtin_amdgcn_mfma_f32_16x16x32_bf16(
              af[kk][i], bg[kk][j], acc[i][j], 0, 0, 0);
    if (t < 7) {
      // Next tile landed before its ds_reads (MFMA above covered latency).
      asm volatile("s_waitcnt vmcnt(0)" : : : "memory");
      __builtin_amdgcn_sched_barrier(0);
    }
  }
#undef STAGEK

  // Epilogue. C/D mapping: col = lane&15, row = (lane>>4)*4 + reg.
  const int colBase = rowB0 + l15;
  const int rowBase = rowA0 + (l4 << 2);
  float xq[4][4];
#pragma unroll
  for (int i = 0; i < 4; ++i)
#pragma unroll
    for (int r = 0; r < 4; ++r) xq[i][r] = xsq[rowBase + (i << 4) + r];
  float wq[4];
#pragma unroll
  for (int j = 0; j < 4; ++j) wq[j] = wsq[colBase + (j << 4)];

#pragma unroll
  for (int i = 0; i < 4; ++i) {
#pragma unroll
    for (int r = 0; r < 4; ++r) {
      const size_t rbase = (size_t)(rowBase + (i << 4) + r) * (size_t)N;
#pragma unroll
      for (int j = 0; j < 4; ++j) {
        float v = xq[i][r] + wq[j] - 2.0f * acc[i][j][r];
        v = fmaxf(v, 0.0f);
        out[rbase + colBase + (j << 4)] = sqrtf(v) * INV_SCALE;
      }
    }
  }
}

extern "C" void kernel_launch(void* const* d_in, const int* in_sizes, int n_in,
                              void* d_out, int out_size, void* d_ws, size_t ws_size,
                              hipStream_t stream) {
  const float* x = (const float*)d_in[0];   // (M, 512) fp32
  const float* w = (const float*)d_in[1];   // (N, 512) fp32
  const int M = in_sizes[0] / K_DIM;        // 8192
  const int N = in_sizes[1] / K_DIM;        // 4096
  float* out = (float*)d_out;

  char* ws = (char*)d_ws;
  ushort* xb = (ushort*)ws;
  ushort* wb = (ushort*)(ws + (size_t)M * K_DIM * 2);
  float* xsq = (float*)(ws + (size_t)M * K_DIM * 2 + (size_t)N * K_DIM * 2);
  float* wsq = xsq + M;

  convert_kernel<<<M + N, 128, 0, stream>>>(x, w, xb, wb, xsq, wsq, M);

  dim3 grid((M >> 6) * (N >> 6));  // 128 * 64 = 8192 blocks, 64 threads
  gemm_dist_kernel<<<grid, 64, 0, stream>>>(xb, wb, xsq, wsq, out, M, N);
}

// Round 18
// 56.640 us; speedup vs baseline: 1.3233x; 1.3233x over previous
//
#include <hip/hip_runtime.h>
#include <hip/hip_bf16.h>

// out[b,w] = relu(sqrt(max(||x_b||^2 + ||w_w||^2 - 2*x_b.w_w, 0)) / sqrt(512))
// M=8192, N=4096, K=512. bf16 MFMA NT-GEMM.
// GEMM: R11/R16 confirmed champion, byte-identical (128x128 tile, BK=64,
// 4 waves, single-buffer 32KB LDS, 2 barriers/K-step, gll width 16, T2
// XOR-swizzle, 2D XCD 16x16 tile-grouping).
// Convert: leaner — one 64-lane wave per row, no LDS/barrier, ushort8 stores,
// 3072 blocks instead of 12288 (convert was ~4us of the 58us total).

typedef __bf16 bf16x8 __attribute__((ext_vector_type(8)));
typedef float f32x4 __attribute__((ext_vector_type(4)));
typedef short short8 __attribute__((ext_vector_type(8)));

#define K_DIM 512
#define INV_SCALE 0.04419417382415922f  // 1/22.627417

__device__ __forceinline__ ushort f2bf(float f) {
  __hip_bfloat16 h = __float2bfloat16(f);
  return __builtin_bit_cast(ushort, h);
}

// One 64-lane wave per row: fp32 -> bf16 (ushort8 store) + sum of squares
// via shuffle butterfly. 4 waves/block, no LDS, no __syncthreads.
__global__ __launch_bounds__(256) void convert_kernel(
    const float* __restrict__ x, const float* __restrict__ w,
    ushort* __restrict__ xb, ushort* __restrict__ wb,
    float* __restrict__ xsq, float* __restrict__ wsq, int M, int NR) {
  const int row = (blockIdx.x << 2) + (threadIdx.x >> 6);
  if (row >= NR) return;
  const int lane = threadIdx.x & 63;
  const float* src; ushort* dst; float* sq; int r;
  if (row < M) { src = x; dst = xb; sq = xsq; r = row; }
  else         { src = w; dst = wb; sq = wsq; r = row - M; }
  const float4* p = reinterpret_cast<const float4*>(src + (size_t)r * K_DIM) + (lane << 1);
  float4 v0 = p[0], v1 = p[1];
  short8 pk;
  pk[0] = (short)f2bf(v0.x); pk[1] = (short)f2bf(v0.y);
  pk[2] = (short)f2bf(v0.z); pk[3] = (short)f2bf(v0.w);
  pk[4] = (short)f2bf(v1.x); pk[5] = (short)f2bf(v1.y);
  pk[6] = (short)f2bf(v1.z); pk[7] = (short)f2bf(v1.w);
  *reinterpret_cast<short8*>(dst + (size_t)r * K_DIM + (lane << 3)) = pk;
  float s = v0.x * v0.x + v0.y * v0.y + v0.z * v0.z + v0.w * v0.w
          + v1.x * v1.x + v1.y * v1.y + v1.z * v1.z + v1.w * v1.w;
#pragma unroll
  for (int o = 32; o > 0; o >>= 1) s += __shfl_xor(s, o, 64);
  if (lane == 0) sq[r] = s;
}

// LDS holds (row, ch) = global(row, ch ^ (row&7)); staging pre-swizzles the
// per-lane global source chunk (linear gll dest), reads XOR with row&7.
// 2-way residual conflict = free (m136).
__global__ void gemm_dist_kernel(
    const ushort* __restrict__ xb, const ushort* __restrict__ wb,
    const float* __restrict__ xsq, const float* __restrict__ wsq,
    float* __restrict__ out, int M, int N) {
  __shared__ ushort Asm[128 * 64];  // 16 KB
  __shared__ ushort Bsm[128 * 64];  // 16 KB

  const int ntN = N >> 7;                 // 32
  const int ntM = M >> 7;                 // 64
  const int nwg = gridDim.x;              // 2048
  const int bid = blockIdx.x;
  int tR, tC;
  if (ntM == 64 && ntN == 32 && nwg == 2048) {
    // 2D XCD grouping: 8 groups (4 rows x 2 cols) of 16x16 tiles.
    const int x = bid & 7;
    const int i = bid >> 3;
    tR = ((x >> 1) << 4) + (i >> 4);
    tC = ((x & 1) << 4) + (i & 15);
  } else {
    const int swz = ((nwg & 7) == 0) ? ((bid & 7) * (nwg >> 3) + (bid >> 3)) : bid;
    tR = swz / ntN;
    tC = swz - tR * ntN;
  }

  const int tid = threadIdx.x;
  const int wid = tid >> 6;
  const int lane = tid & 63;
  const int wr = wid >> 1, wc = wid & 1;
  const int l15 = lane & 15, l4 = lane >> 4;

  const int rowA0 = tR << 7;
  const int rowB0 = tC << 7;

  f32x4 acc[4][4] = {};

  // Staging map: wave wid covers tile rows [wid*32, wid*32+32) in 4 calls of
  // 8 rows each; lane l -> row +(l>>3). Source chunk pre-swizzled (l&7)^(l>>3)
  // (row&7 == l>>3 here) so the linear gll dest yields the swizzled layout.
  const int srow = (wid << 5) + (lane >> 3);
  const int scol = ((lane & 7) ^ (lane >> 3)) << 3;
  const ushort* gA = xb + (size_t)(rowA0 + srow) * K_DIM + scol;
  const ushort* gB = wb + (size_t)(rowB0 + srow) * K_DIM + scol;

  for (int kt = 0; kt < K_DIM; kt += 64) {
#pragma unroll
    for (int c = 0; c < 4; ++c) {
      const int r0 = (wid << 5) + (c << 3);  // wave-uniform LDS row base
      __builtin_amdgcn_global_load_lds(
          (const __attribute__((address_space(1))) void*)(gA + (size_t)(c * 8) * K_DIM + kt),
          (__attribute__((address_space(3))) void*)&Asm[r0 * 64], 16, 0, 0);
      __builtin_amdgcn_global_load_lds(
          (const __attribute__((address_space(1))) void*)(gB + (size_t)(c * 8) * K_DIM + kt),
          (__attribute__((address_space(3))) void*)&Bsm[r0 * 64], 16, 0, 0);
    }
    __syncthreads();  // compiler emits vmcnt(0) drain before s_barrier

    const int axor = l15 & 7;  // row&7 for this lane's fragment rows
#pragma unroll
    for (int kk = 0; kk < 2; ++kk) {
      bf16x8 af[4], bfr[4];
      const int cx = (((kk << 2) + l4) ^ axor) << 3;  // swizzled chunk offset
#pragma unroll
      for (int i = 0; i < 4; ++i) {
        af[i]  = *reinterpret_cast<const bf16x8*>(
            &Asm[((wr << 6) + (i << 4) + l15) * 64 + cx]);
        bfr[i] = *reinterpret_cast<const bf16x8*>(
            &Bsm[((wc << 6) + (i << 4) + l15) * 64 + cx]);
      }
#pragma unroll
      for (int i = 0; i < 4; ++i)
#pragma unroll
        for (int j = 0; j < 4; ++j)
          acc[i][j] = __builtin_amdgcn_mfma_f32_16x16x32_bf16(af[i], bfr[j], acc[i][j], 0, 0, 0);
    }
    __syncthreads();
  }

  // Epilogue. C/D mapping: col = lane&15, row = (lane>>4)*4 + reg.
  const int colBase = rowB0 + (wc << 6) + l15;
  const int rowBase = rowA0 + (wr << 6) + (l4 << 2);
  float xq[4][4];
#pragma unroll
  for (int i = 0; i < 4; ++i)
#pragma unroll
    for (int r = 0; r < 4; ++r) xq[i][r] = xsq[rowBase + (i << 4) + r];
  float wq[4];
#pragma unroll
  for (int j = 0; j < 4; ++j) wq[j] = wsq[colBase + (j << 4)];

#pragma unroll
  for (int i = 0; i < 4; ++i) {
#pragma unroll
    for (int r = 0; r < 4; ++r) {
      const size_t rbase = (size_t)(rowBase + (i << 4) + r) * (size_t)N;
#pragma unroll
      for (int j = 0; j < 4; ++j) {
        float v = xq[i][r] + wq[j] - 2.0f * acc[i][j][r];
        v = fmaxf(v, 0.0f);
        out[rbase + colBase + (j << 4)] = sqrtf(v) * INV_SCALE;
      }
    }
  }
}

extern "C" void kernel_launch(void* const* d_in, const int* in_sizes, int n_in,
                              void* d_out, int out_size, void* d_ws, size_t ws_size,
                              hipStream_t stream) {
  const float* x = (const float*)d_in[0];   // (M, 512) fp32
  const float* w = (const float*)d_in[1];   // (N, 512) fp32
  const int M = in_sizes[0] / K_DIM;        // 8192
  const int N = in_sizes[1] / K_DIM;        // 4096
  float* out = (float*)d_out;

  char* ws = (char*)d_ws;
  ushort* xb = (ushort*)ws;
  ushort* wb = (ushort*)(ws + (size_t)M * K_DIM * 2);
  float* xsq = (float*)(ws + (size_t)M * K_DIM * 2 + (size_t)N * K_DIM * 2);
  float* wsq = xsq + M;

  const int NR = M + N;                     // 12288 rows, 4 waves/block
  convert_kernel<<<(NR + 3) / 4, 256, 0, stream>>>(x, w, xb, wb, xsq, wsq, M, NR);

  dim3 grid((M >> 7) * (N >> 7));  // 64 * 32 = 2048
  gemm_dist_kernel<<<grid, 256, 0, stream>>>(xb, wb, xsq, wsq, out, M, N);
}